// Round 3
// baseline (161.402 us; speedup 1.0000x reference)
//
#include <hip/hip_runtime.h>
#include <stdint.h>

typedef unsigned short u16;
typedef u16 u16x4 __attribute__((ext_vector_type(4)));
typedef u16 u16x8 __attribute__((ext_vector_type(8)));
typedef __bf16 bf16x8 __attribute__((ext_vector_type(8)));
typedef float f32x4 __attribute__((ext_vector_type(4)));

#define NSER 4096
#define KDIM 4096
#define NCOLS 288                 // 264 padded to 288 (divisible by BN=96)
#define MATSZ (NCOLS * NSER)      // elements per transposed bf16 mat buffer
#define PE ((size_t)NCOLS * NSER) // fp32 partial buffer elements (1,179,648)

__device__ __forceinline__ u16 f2bf(float f) {
  uint32_t u = __builtin_bit_cast(uint32_t, f);
  u += 0x7FFFu + ((u >> 16) & 1u);   // RNE; inputs are never NaN
  return (u16)(u >> 16);
}
__device__ __forceinline__ float bf2f(u16 h) {
  return __builtin_bit_cast(float, (uint32_t)h << 16);
}

typedef const void __attribute__((address_space(1)))* gas1p;
typedef void __attribute__((address_space(3)))* las3p;

__device__ __forceinline__ void gload16(const void* g, void* l) {
  __builtin_amdgcn_global_load_lds((gas1p)g, (las3p)l, 16, 0, 0);
}

// ---------------- build X^T [288][4096] bf16 ----------------
// Xt[f*4+b][n] = xs[b,n,f];  f<2 -> inputs[b][n*2+f], f>=2 -> state[b][n*64+(f-2)]
__global__ __launch_bounds__(256) void k_build_x(const float* __restrict__ inputs,
                                                 const float* __restrict__ state,
                                                 u16* __restrict__ xb) {
  __shared__ float tile[64][65];
  const int nt = blockIdx.x, b = blockIdx.y;
  const int n0 = nt * 64;
  const int t = threadIdx.x;
  {
    const int i = t >> 2;
    const int c0 = (t & 3) * 16;
    const float* sp = state + ((int64_t)b * NSER + (n0 + i)) * 64 + c0;
    #pragma unroll
    for (int q = 0; q < 4; ++q) {
      float4 v = *(const float4*)(sp + q * 4);
      tile[i][c0 + q * 4 + 0] = v.x;
      tile[i][c0 + q * 4 + 1] = v.y;
      tile[i][c0 + q * 4 + 2] = v.z;
      tile[i][c0 + q * 4 + 3] = v.w;
    }
  }
  __syncthreads();
  const int wv = t >> 6, lane = t & 63;
  #pragma unroll
  for (int it = 0; it < 16; ++it) {
    const int d = wv + 4 * it;  // 0..63
    xb[(size_t)((2 + d) * 4 + b) * NSER + n0 + lane] = f2bf(tile[lane][d]);
  }
  if (t < 128) {
    const int c = t >> 6, j = t & 63;
    xb[(size_t)(c * 4 + b) * NSER + n0 + j] =
        f2bf(inputs[(int64_t)b * (NSER * 2) + (int64_t)(n0 + j) * 2 + c]);
  }
  if (b == 0) {  // zero pad rows 264..287
    for (int idx = t; idx < 24 * 64; idx += 256)
      xb[(size_t)(264 + idx / 64) * NSER + n0 + (idx & 63)] = 0;
  }
}

// ---------------- GEMM: P[z][j][i] = sum_k A[i][k] * B^T[j][k] ----------------
// A is fp32 in global (converted to bf16 during reg-staged LDS write);
// B is bf16 (global_load_lds with pre-swizzled source). Split-K: KC=4 chunks.
#define BM 128
#define BN 96
#define BK 64
#define KC 4
#define ABYTES (BM * BK * 2)      // 16384
#define BBYTES (BN * BK * 2)      // 12288
#define BUFSZ  (ABYTES + BBYTES)  // 28672

__global__ __launch_bounds__(256) void k_gemm(const float* __restrict__ A0f,
                                              const float* __restrict__ A1f,
                                              const u16* __restrict__ Bm,
                                              float* __restrict__ Pb) {
  int kc = blockIdx.z;
  const float* Af = A0f;
  if (kc >= KC) { Af = A1f; kc -= KC; }
  const int i0 = blockIdx.x * BM;   // x fastest: col/kc-blocks of same A panel share XCD
  const int j0 = blockIdx.y * BN;
  const int t = threadIdx.x;
  const int wid = t >> 6, lane = t & 63;
  const int NKT = KDIM / KC / BK;   // 16
  const int k0 = kc * (KDIM / KC);

  __shared__ char smem[2 * BUFSZ];

  // A staging: fp32 global source (linear), swizzled LDS byte dest
  int a_grow[4], a_ldst[4];
  #pragma unroll
  for (int s = 0; s < 4; ++s) {
    const int row = (wid * 4 + s) * 8 + (lane >> 3);        // 0..127
    a_grow[s] = row * KDIM + (lane & 7) * 8;                // float offset
    a_ldst[s] = row * 128 + 16 * ((lane & 7) ^ (row & 7));  // byte offset in A half
  }
  // B staging: pre-swizzled global source, linear LDS dest (global_load_lds)
  int b_src[3];
  #pragma unroll
  for (int s = 0; s < 3; ++s) {
    const int row = (wid * 3 + s) * 8 + (lane >> 3);        // 0..95
    b_src[s] = row * (KDIM * 2) + 16 * ((lane & 7) ^ (row & 7));
  }
  const float* Ag = Af + (int64_t)i0 * KDIM + k0;
  const char* Bg = (const char*)Bm + ((int64_t)j0 * KDIM + k0) * 2;

  // fragment LDS read offsets (swizzled)
  int aoffs[4], axors[4];
  #pragma unroll
  for (int mf = 0; mf < 4; ++mf) {
    const int row = (wid >> 1) * 64 + mf * 16 + (lane & 15);
    aoffs[mf] = row * 128;
    axors[mf] = (row & 7) << 4;
  }
  int boffs[3], bxors[3];
  #pragma unroll
  for (int nf = 0; nf < 3; ++nf) {
    const int row = (wid & 1) * 48 + nf * 16 + (lane & 15);
    boffs[nf] = ABYTES + row * 128;
    bxors[nf] = (row & 7) << 4;
  }
  const int klane = (lane >> 4) * 16;

  f32x4 acc[4][3];
  #pragma unroll
  for (int mf = 0; mf < 4; ++mf)
    #pragma unroll
    for (int nf = 0; nf < 3; ++nf)
      acc[mf][nf] = (f32x4){0.f, 0.f, 0.f, 0.f};

  f32x4 areg[4][2];

  // prologue: stage kt=0 into buf 0
  #pragma unroll
  for (int s = 0; s < 4; ++s) {
    areg[s][0] = *(const f32x4*)(Ag + a_grow[s]);
    areg[s][1] = *(const f32x4*)(Ag + a_grow[s] + 4);
  }
  #pragma unroll
  for (int s = 0; s < 3; ++s)
    gload16(Bg + b_src[s], smem + ABYTES + (wid * 3 + s) * 1024);
  #pragma unroll
  for (int s = 0; s < 4; ++s) {
    u16x8 w;
    #pragma unroll
    for (int q = 0; q < 4; ++q) { w[q] = f2bf(areg[s][0][q]); w[4 + q] = f2bf(areg[s][1][q]); }
    *(u16x8*)(smem + a_ldst[s]) = w;
  }
  __syncthreads();

  for (int kt = 0; kt < NKT; ++kt) {
    const int cur = kt & 1;
    char* sbuf = smem + (cur ^ 1) * BUFSZ;
    if (kt + 1 < NKT) {
      const float* Ak = Ag + (kt + 1) * BK;
      const char* Bk = Bg + (kt + 1) * (BK * 2);
      #pragma unroll
      for (int s = 0; s < 4; ++s) {           // issue A reg-loads first (oldest vmcnt)
        areg[s][0] = *(const f32x4*)(Ak + a_grow[s]);
        areg[s][1] = *(const f32x4*)(Ak + a_grow[s] + 4);
      }
      #pragma unroll
      for (int s = 0; s < 3; ++s)
        gload16(Bk + b_src[s], sbuf + ABYTES + (wid * 3 + s) * 1024);
    }
    const char* sb = smem + cur * BUFSZ;
    #pragma unroll
    for (int kk = 0; kk < 2; ++kk) {
      const int kb = kk * 64 + klane;
      bf16x8 af[4], bfv[3];
      #pragma unroll
      for (int mf = 0; mf < 4; ++mf)
        af[mf] = *(const bf16x8*)(sb + aoffs[mf] + (kb ^ axors[mf]));
      #pragma unroll
      for (int nf = 0; nf < 3; ++nf)
        bfv[nf] = *(const bf16x8*)(sb + boffs[nf] + (kb ^ bxors[nf]));
      #pragma unroll
      for (int mf = 0; mf < 4; ++mf)
        #pragma unroll
        for (int nf = 0; nf < 3; ++nf)
          acc[mf][nf] = __builtin_amdgcn_mfma_f32_16x16x32_bf16(af[mf], bfv[nf],
                                                                acc[mf][nf], 0, 0, 0);
    }
    if (kt + 1 < NKT) {  // write-late: A regs -> LDS after compute (vmcnt hidden by MFMA)
      #pragma unroll
      for (int s = 0; s < 4; ++s) {
        u16x8 w;
        #pragma unroll
        for (int q = 0; q < 4; ++q) { w[q] = f2bf(areg[s][0][q]); w[4 + q] = f2bf(areg[s][1][q]); }
        *(u16x8*)(sbuf + a_ldst[s]) = w;
      }
    }
    __syncthreads();
  }

  // epilogue: fp32 partials P[z][j][i]  (C/D frag: col(j)=lane&15, row(i)=(lane>>4)*4+r)
  float* Pp = Pb + (size_t)blockIdx.z * PE;
  #pragma unroll
  for (int mf = 0; mf < 4; ++mf) {
    const int i = i0 + (wid >> 1) * 64 + mf * 16 + ((lane >> 4) << 2);
    #pragma unroll
    for (int nf = 0; nf < 3; ++nf) {
      const int j = j0 + (wid & 1) * 48 + nf * 16 + (lane & 15);
      *(f32x4*)(Pp + (size_t)j * NSER + i) = acc[mf][nf];
    }
  }
}

// ---------------- reduce 4 fp32 partials -> bf16 mat ----------------
__global__ __launch_bounds__(256) void k_reduce(const float* __restrict__ P,
                                                u16* __restrict__ o) {
  const size_t i = ((size_t)blockIdx.x * 256 + threadIdx.x) * 4;
  f32x4 s = *(const f32x4*)(P + i);
  #pragma unroll
  for (int k = 1; k < 4; ++k)
    s += *(const f32x4*)(P + (size_t)k * PE + i);
  u16x4 w;
  #pragma unroll
  for (int r = 0; r < 4; ++r) w[r] = f2bf(s[r]);
  *(u16x4*)(o + i) = w;
}

// ---------------- final: out[b,n,o] = X*W0' + m1*W1' + m2*W2' + m3*W3' + m4*W4' + bias
// m2 comes as 4 fp32 partials at P[0..3], m4 at P[4..7].
__global__ __launch_bounds__(256) void k_final(const float* __restrict__ weight,
                                               const float* __restrict__ biases,
                                               const u16* __restrict__ Xb,
                                               const u16* __restrict__ m1b,
                                               const u16* __restrict__ m3b,
                                               const float* __restrict__ P,
                                               float* __restrict__ out) {
  __shared__ float w2[330][32];
  const int nt = blockIdx.x, b = blockIdx.y, oh = blockIdx.z;
  const int n0 = nt * 64;
  const int t = threadIdx.x;
  const int lane = t & 63, wv = t >> 6;
  {
    const int ol = t & 31;
    const int o = oh * 32 + ol;
    for (int f = t >> 5; f < 66; f += 8) {
      const float v0 = weight[(f * 5 + 0) * 64 + o];
      const float v1 = weight[(f * 5 + 1) * 64 + o];
      const float v2 = weight[(f * 5 + 2) * 64 + o];
      const float v3 = weight[(f * 5 + 3) * 64 + o];
      const float v4 = weight[(f * 5 + 4) * 64 + o];
      w2[f * 5 + 0][ol] = v0 - v2;   // X coefficient
      w2[f * 5 + 1][ol] = v1 - v4;   // m1
      w2[f * 5 + 2][ol] = 2.f * v2;  // m2
      w2[f * 5 + 3][ol] = v3;        // m3
      w2[f * 5 + 4][ol] = 2.f * v4;  // m4
    }
  }
  __syncthreads();
  const int ob = oh * 32 + wv * 8;
  float acc[8];
  #pragma unroll
  for (int i = 0; i < 8; ++i) acc[i] = biases[ob + i];
  for (int f = 0; f < 66; ++f) {
    const size_t base = (size_t)(f * 4 + b) * NSER + n0 + lane;
    float y[5];
    y[0] = bf2f(Xb[base]);
    y[1] = bf2f(m1b[base]);
    y[2] = P[base] + P[PE + base] + P[2 * PE + base] + P[3 * PE + base];
    y[3] = bf2f(m3b[base]);
    y[4] = P[4 * PE + base] + P[5 * PE + base] + P[6 * PE + base] + P[7 * PE + base];
    #pragma unroll
    for (int mat = 0; mat < 5; ++mat) {
      const float* wr = &w2[f * 5 + mat][wv * 8];
      #pragma unroll
      for (int i = 0; i < 8; ++i) acc[i] = fmaf(y[mat], wr[i], acc[i]);
    }
  }
  float* op = out + (size_t)b * (NSER * 64) + (size_t)(n0 + lane) * 64 + ob;
  #pragma unroll
  for (int i = 0; i < 8; ++i) op[i] = acc[i];
}

extern "C" void kernel_launch(void* const* d_in, const int* in_sizes, int n_in,
                              void* d_out, int out_size, void* d_ws, size_t ws_size,
                              hipStream_t stream) {
  const float* inputs = (const float*)d_in[0];
  const float* state  = (const float*)d_in[1];
  const float* s0     = (const float*)d_in[2];
  const float* s1     = (const float*)d_in[3];
  const float* weight = (const float*)d_in[4];
  const float* biases = (const float*)d_in[5];
  float* out = (float*)d_out;

  char* ws = (char*)d_ws;
  u16* Xb  = (u16*)ws;                          // 2,359,296 B
  u16* m1b = Xb + MATSZ;                        // 2,359,296 B
  u16* m3b = m1b + MATSZ;                       // 2,359,296 B
  float* P = (float*)(ws + (size_t)3 * 2359296);// 8 x 4,718,592 B  (total ~44.8 MB)

  k_build_x<<<dim3(64, 4, 1), 256, 0, stream>>>(inputs, state, Xb);
  // m1 = S0 @ X          -> partials P[0..3]
  k_gemm<<<dim3(32, 3, 4), 256, 0, stream>>>(s0, s0, Xb, P);
  k_reduce<<<dim3(1152, 1, 1), 256, 0, stream>>>(P, m1b);
  // m2 = S0 @ m1 -> P[0..3] (kept fp32 for k_final); m3 = S1 @ m1 -> P[4..7]
  k_gemm<<<dim3(32, 3, 8), 256, 0, stream>>>(s0, s1, m1b, P);
  k_reduce<<<dim3(1152, 1, 1), 256, 0, stream>>>(P + 4 * PE, m3b);
  // m4 = S1 @ m3 -> P[4..7] (m3 partials already reduced; m2 partials in P[0..3] survive)
  k_gemm<<<dim3(32, 3, 4), 256, 0, stream>>>(s1, s1, m3b, P + 4 * PE);
  // epilogue GEMM with folded Chebyshev combinations; m2/m4 summed from fp32 partials
  k_final<<<dim3(64, 4, 2), 256, 0, stream>>>(weight, biases, Xb, m1b, m3b, P, out);
}

// Round 4
// 140.438 us; speedup vs baseline: 1.1493x; 1.1493x over previous
//
#include <hip/hip_runtime.h>
#include <stdint.h>

typedef unsigned short u16;
typedef u16 u16x4 __attribute__((ext_vector_type(4)));
typedef u16 u16x8 __attribute__((ext_vector_type(8)));
typedef __bf16 bf16x8 __attribute__((ext_vector_type(8)));
typedef float f32x4 __attribute__((ext_vector_type(4)));

#define NSER 4096
#define KDIM 4096
#define NCOLS 288                 // 264 padded to 288 (divisible by BN=96)
#define MATSZ (NCOLS * NSER)      // elements per transposed bf16 mat buffer
#define PE ((size_t)NCOLS * NSER) // fp32 partial buffer elements (1,179,648)

__device__ __forceinline__ u16 f2bf(float f) {
  uint32_t u = __builtin_bit_cast(uint32_t, f);
  u += 0x7FFFu + ((u >> 16) & 1u);   // RNE; inputs are never NaN
  return (u16)(u >> 16);
}
__device__ __forceinline__ float bf2f(u16 h) {
  return __builtin_bit_cast(float, (uint32_t)h << 16);
}

typedef const void __attribute__((address_space(1)))* gas1p;
typedef void __attribute__((address_space(3)))* las3p;

__device__ __forceinline__ void gload16(const void* g, void* l) {
  __builtin_amdgcn_global_load_lds((gas1p)g, (las3p)l, 16, 0, 0);
}

// ---------------- build X^T [288][4096] bf16 ----------------
// Xt[f*4+b][n] = xs[b,n,f];  f<2 -> inputs[b][n*2+f], f>=2 -> state[b][n*64+(f-2)]
__global__ __launch_bounds__(256) void k_build_x(const float* __restrict__ inputs,
                                                 const float* __restrict__ state,
                                                 u16* __restrict__ xb) {
  __shared__ float tile[64][65];
  const int nt = blockIdx.x, b = blockIdx.y;
  const int n0 = nt * 64;
  const int t = threadIdx.x;
  {
    const int i = t >> 2;
    const int c0 = (t & 3) * 16;
    const float* sp = state + ((int64_t)b * NSER + (n0 + i)) * 64 + c0;
    #pragma unroll
    for (int q = 0; q < 4; ++q) {
      float4 v = *(const float4*)(sp + q * 4);
      tile[i][c0 + q * 4 + 0] = v.x;
      tile[i][c0 + q * 4 + 1] = v.y;
      tile[i][c0 + q * 4 + 2] = v.z;
      tile[i][c0 + q * 4 + 3] = v.w;
    }
  }
  __syncthreads();
  const int wv = t >> 6, lane = t & 63;
  #pragma unroll
  for (int it = 0; it < 16; ++it) {
    const int d = wv + 4 * it;  // 0..63
    xb[(size_t)((2 + d) * 4 + b) * NSER + n0 + lane] = f2bf(tile[lane][d]);
  }
  if (t < 128) {
    const int c = t >> 6, j = t & 63;
    xb[(size_t)(c * 4 + b) * NSER + n0 + j] =
        f2bf(inputs[(int64_t)b * (NSER * 2) + (int64_t)(n0 + j) * 2 + c]);
  }
  if (b == 0) {  // zero pad rows 264..287
    for (int idx = t; idx < 24 * 64; idx += 256)
      xb[(size_t)(264 + idx / 64) * NSER + n0 + (idx & 63)] = 0;
  }
}

// ---------------- GEMM: P[z][j][i] = sum_k A[i][k] * B^T[j][k] ----------------
// A is fp32 in global (converted to bf16 during reg-staged LDS write);
// B is bf16 (global_load_lds with pre-swizzled source). Split-K: KC=4 chunks.
// BM=64 / 768 blocks-per-unit / 40KB LDS: 4 resident blocks per CU for latency hiding.
#define BM 64
#define BN 96
#define BK 64
#define KC 4
#define ABYTES (BM * BK * 2)      // 8192
#define BBYTES (BN * BK * 2)      // 12288
#define BUFSZ  (ABYTES + BBYTES)  // 20480

__global__ __launch_bounds__(256) void k_gemm(const float* __restrict__ A0f,
                                              const float* __restrict__ A1f,
                                              const u16* __restrict__ Bm,
                                              float* __restrict__ Pb) {
  int kc = blockIdx.z;
  const float* Af = A0f;
  if (kc >= KC) { Af = A1f; kc -= KC; }
  const int i0 = blockIdx.x * BM;   // x fastest: j-blocks of same A panel differ by 64 in id -> same XCD
  const int j0 = blockIdx.y * BN;
  const int t = threadIdx.x;
  const int wid = t >> 6, lane = t & 63;
  const int NKT = KDIM / KC / BK;   // 16
  const int k0 = kc * (KDIM / KC);

  __shared__ char smem[2 * BUFSZ];

  // A staging: fp32 global source (linear), swizzled LDS byte dest. 2 slots x 32 rows.
  int a_grow[2], a_ldst[2];
  #pragma unroll
  for (int s = 0; s < 2; ++s) {
    const int row = (wid * 2 + s) * 8 + (lane >> 3);        // 0..63
    a_grow[s] = row * KDIM + (lane & 7) * 8;                // float offset
    a_ldst[s] = row * 128 + 16 * ((lane & 7) ^ (row & 7));  // byte offset in A half
  }
  // B staging: pre-swizzled global source, linear LDS dest (global_load_lds). 3 slots x 32 rows.
  int b_src[3];
  #pragma unroll
  for (int s = 0; s < 3; ++s) {
    const int row = (wid * 3 + s) * 8 + (lane >> 3);        // 0..95
    b_src[s] = row * (KDIM * 2) + 16 * ((lane & 7) ^ (row & 7));
  }
  const float* Ag = Af + (int64_t)i0 * KDIM + k0;
  const char* Bg = (const char*)Bm + ((int64_t)j0 * KDIM + k0) * 2;

  // fragment LDS read offsets (swizzled). Wave tile 32x48: 2 mf x 3 nf.
  int aoffs[2], axors[2];
  #pragma unroll
  for (int mf = 0; mf < 2; ++mf) {
    const int row = (wid >> 1) * 32 + mf * 16 + (lane & 15);
    aoffs[mf] = row * 128;
    axors[mf] = (row & 7) << 4;
  }
  int boffs[3], bxors[3];
  #pragma unroll
  for (int nf = 0; nf < 3; ++nf) {
    const int row = (wid & 1) * 48 + nf * 16 + (lane & 15);
    boffs[nf] = ABYTES + row * 128;
    bxors[nf] = (row & 7) << 4;
  }
  const int klane = (lane >> 4) * 16;

  f32x4 acc[2][3];
  #pragma unroll
  for (int mf = 0; mf < 2; ++mf)
    #pragma unroll
    for (int nf = 0; nf < 3; ++nf)
      acc[mf][nf] = (f32x4){0.f, 0.f, 0.f, 0.f};

  f32x4 areg[2][2];

  // prologue: stage kt=0 into buf 0
  #pragma unroll
  for (int s = 0; s < 2; ++s) {
    areg[s][0] = *(const f32x4*)(Ag + a_grow[s]);
    areg[s][1] = *(const f32x4*)(Ag + a_grow[s] + 4);
  }
  #pragma unroll
  for (int s = 0; s < 3; ++s)
    gload16(Bg + b_src[s], smem + ABYTES + (wid * 3 + s) * 1024);
  #pragma unroll
  for (int s = 0; s < 2; ++s) {
    u16x8 w;
    #pragma unroll
    for (int q = 0; q < 4; ++q) { w[q] = f2bf(areg[s][0][q]); w[4 + q] = f2bf(areg[s][1][q]); }
    *(u16x8*)(smem + a_ldst[s]) = w;
  }
  __syncthreads();

  for (int kt = 0; kt < NKT; ++kt) {
    const int cur = kt & 1;
    char* sbuf = smem + (cur ^ 1) * BUFSZ;
    if (kt + 1 < NKT) {
      const float* Ak = Ag + (kt + 1) * BK;
      const char* Bk = Bg + (kt + 1) * (BK * 2);
      #pragma unroll
      for (int s = 0; s < 2; ++s) {           // issue A reg-loads first (oldest vmcnt)
        areg[s][0] = *(const f32x4*)(Ak + a_grow[s]);
        areg[s][1] = *(const f32x4*)(Ak + a_grow[s] + 4);
      }
      #pragma unroll
      for (int s = 0; s < 3; ++s)
        gload16(Bk + b_src[s], sbuf + ABYTES + (wid * 3 + s) * 1024);
    }
    const char* sb = smem + cur * BUFSZ;
    #pragma unroll
    for (int kk = 0; kk < 2; ++kk) {
      const int kb = kk * 64 + klane;
      bf16x8 af[2], bfv[3];
      #pragma unroll
      for (int mf = 0; mf < 2; ++mf)
        af[mf] = *(const bf16x8*)(sb + aoffs[mf] + (kb ^ axors[mf]));
      #pragma unroll
      for (int nf = 0; nf < 3; ++nf)
        bfv[nf] = *(const bf16x8*)(sb + boffs[nf] + (kb ^ bxors[nf]));
      #pragma unroll
      for (int mf = 0; mf < 2; ++mf)
        #pragma unroll
        for (int nf = 0; nf < 3; ++nf)
          acc[mf][nf] = __builtin_amdgcn_mfma_f32_16x16x32_bf16(af[mf], bfv[nf],
                                                                acc[mf][nf], 0, 0, 0);
    }
    if (kt + 1 < NKT) {  // write-late: A regs -> LDS after compute (vmcnt hidden by MFMA)
      #pragma unroll
      for (int s = 0; s < 2; ++s) {
        u16x8 w;
        #pragma unroll
        for (int q = 0; q < 4; ++q) { w[q] = f2bf(areg[s][0][q]); w[4 + q] = f2bf(areg[s][1][q]); }
        *(u16x8*)(sbuf + a_ldst[s]) = w;
      }
    }
    __syncthreads();
  }

  // epilogue: fp32 partials P[z][j][i]  (C/D frag: col(j)=lane&15, row(i)=(lane>>4)*4+r)
  float* Pp = Pb + (size_t)blockIdx.z * PE;
  #pragma unroll
  for (int mf = 0; mf < 2; ++mf) {
    const int i = i0 + (wid >> 1) * 32 + mf * 16 + ((lane >> 4) << 2);
    #pragma unroll
    for (int nf = 0; nf < 3; ++nf) {
      const int j = j0 + (wid & 1) * 48 + nf * 16 + (lane & 15);
      *(f32x4*)(Pp + (size_t)j * NSER + i) = acc[mf][nf];
    }
  }
}

// ---------------- reduce 4 fp32 partials -> bf16 mat ----------------
__global__ __launch_bounds__(256) void k_reduce(const float* __restrict__ P,
                                                u16* __restrict__ o) {
  const size_t i = ((size_t)blockIdx.x * 256 + threadIdx.x) * 4;
  f32x4 s = *(const f32x4*)(P + i);
  #pragma unroll
  for (int k = 1; k < 4; ++k)
    s += *(const f32x4*)(P + (size_t)k * PE + i);
  u16x4 w;
  #pragma unroll
  for (int r = 0; r < 4; ++r) w[r] = f2bf(s[r]);
  *(u16x4*)(o + i) = w;
}

// ---------------- final: out[b,n,o] = X*W0' + m1*W1' + m2*W2' + m3*W3' + m4*W4' + bias
// m2 comes as 4 fp32 partials at P[0..3], m4 at P[4..7].
__global__ __launch_bounds__(256) void k_final(const float* __restrict__ weight,
                                               const float* __restrict__ biases,
                                               const u16* __restrict__ Xb,
                                               const u16* __restrict__ m1b,
                                               const u16* __restrict__ m3b,
                                               const float* __restrict__ P,
                                               float* __restrict__ out) {
  __shared__ float w2[330][32];
  const int nt = blockIdx.x, b = blockIdx.y, oh = blockIdx.z;
  const int n0 = nt * 64;
  const int t = threadIdx.x;
  const int lane = t & 63, wv = t >> 6;
  {
    const int ol = t & 31;
    const int o = oh * 32 + ol;
    for (int f = t >> 5; f < 66; f += 8) {
      const float v0 = weight[(f * 5 + 0) * 64 + o];
      const float v1 = weight[(f * 5 + 1) * 64 + o];
      const float v2 = weight[(f * 5 + 2) * 64 + o];
      const float v3 = weight[(f * 5 + 3) * 64 + o];
      const float v4 = weight[(f * 5 + 4) * 64 + o];
      w2[f * 5 + 0][ol] = v0 - v2;   // X coefficient
      w2[f * 5 + 1][ol] = v1 - v4;   // m1
      w2[f * 5 + 2][ol] = 2.f * v2;  // m2
      w2[f * 5 + 3][ol] = v3;        // m3
      w2[f * 5 + 4][ol] = 2.f * v4;  // m4
    }
  }
  __syncthreads();
  const int ob = oh * 32 + wv * 8;
  float acc[8];
  #pragma unroll
  for (int i = 0; i < 8; ++i) acc[i] = biases[ob + i];
  for (int f = 0; f < 66; ++f) {
    const size_t base = (size_t)(f * 4 + b) * NSER + n0 + lane;
    float y[5];
    y[0] = bf2f(Xb[base]);
    y[1] = bf2f(m1b[base]);
    y[2] = P[base] + P[PE + base] + P[2 * PE + base] + P[3 * PE + base];
    y[3] = bf2f(m3b[base]);
    y[4] = P[4 * PE + base] + P[5 * PE + base] + P[6 * PE + base] + P[7 * PE + base];
    #pragma unroll
    for (int mat = 0; mat < 5; ++mat) {
      const float* wr = &w2[f * 5 + mat][wv * 8];
      #pragma unroll
      for (int i = 0; i < 8; ++i) acc[i] = fmaf(y[mat], wr[i], acc[i]);
    }
  }
  float* op = out + (size_t)b * (NSER * 64) + (size_t)(n0 + lane) * 64 + ob;
  #pragma unroll
  for (int i = 0; i < 8; ++i) op[i] = acc[i];
}

extern "C" void kernel_launch(void* const* d_in, const int* in_sizes, int n_in,
                              void* d_out, int out_size, void* d_ws, size_t ws_size,
                              hipStream_t stream) {
  const float* inputs = (const float*)d_in[0];
  const float* state  = (const float*)d_in[1];
  const float* s0     = (const float*)d_in[2];
  const float* s1     = (const float*)d_in[3];
  const float* weight = (const float*)d_in[4];
  const float* biases = (const float*)d_in[5];
  float* out = (float*)d_out;

  char* ws = (char*)d_ws;
  u16* Xb  = (u16*)ws;                          // 2,359,296 B
  u16* m1b = Xb + MATSZ;                        // 2,359,296 B
  u16* m3b = m1b + MATSZ;                       // 2,359,296 B
  float* P = (float*)(ws + (size_t)3 * 2359296);// 8 x 4,718,592 B  (total ~44.8 MB)

  k_build_x<<<dim3(64, 4, 1), 256, 0, stream>>>(inputs, state, Xb);
  // m1 = S0 @ X          -> partials P[0..3]
  k_gemm<<<dim3(64, 3, 4), 256, 0, stream>>>(s0, s0, Xb, P);
  k_reduce<<<dim3(1152, 1, 1), 256, 0, stream>>>(P, m1b);
  // m2 = S0 @ m1 -> P[0..3] (kept fp32 for k_final); m3 = S1 @ m1 -> P[4..7]
  k_gemm<<<dim3(64, 3, 8), 256, 0, stream>>>(s0, s1, m1b, P);
  k_reduce<<<dim3(1152, 1, 1), 256, 0, stream>>>(P + 4 * PE, m3b);
  // m4 = S1 @ m3 -> P[4..7] (m3 partials already reduced; m2 partials in P[0..3] survive)
  k_gemm<<<dim3(64, 3, 4), 256, 0, stream>>>(s1, s1, m3b, P + 4 * PE);
  // epilogue GEMM with folded Chebyshev combinations; m2/m4 summed from fp32 partials
  k_final<<<dim3(64, 4, 2), 256, 0, stream>>>(weight, biases, Xb, m1b, m3b, P, out);
}